// Round 1
// baseline (597.560 us; speedup 1.0000x reference)
//
#include <hip/hip_runtime.h>
#include <math.h>

namespace {

constexpr int L = 10;

// compile-time sqrt (Newton), converges to <=1 ulp for our range
constexpr double csqrt(double x) {
  double y = x > 1.0 ? x : 1.0;
  for (int i = 0; i < 64; ++i) y = 0.5 * (y + x / y);
  return y;
}
constexpr double dfact(int n) {
  double r = 1.0;
  for (int i = 2; i <= n; ++i) r *= (double)i;
  return r;
}

struct Tab { float c[L][L]; };
constexpr Tab make_tab() {
  Tab t{};
  constexpr double FOUR_PI = 12.566370614359172;
  constexpr double SQRT2  = 1.4142135623730951;
  for (int l = 0; l < L; ++l)
    for (int m = 0; m <= l; ++m) {
      double K = csqrt((2.0 * l + 1.0) / FOUR_PI * dfact(l - m) / dfact(l + m));
      t.c[l][m] = (float)((m == 0 ? 1.0 : SQRT2) * K);
    }
  return t;
}
constexpr Tab TAB = make_tab();

__global__ __launch_bounds__(256) void sh_kernel(const float2* __restrict__ ll,
                                                 float* __restrict__ out, int N) {
  int i = blockIdx.x * blockDim.x + threadIdx.x;
  if (i >= N) return;

  float2 p = ll[i];  // coalesced 8B/lane
  constexpr float DEG2RAD = 0.017453292519943295f;
  float phi   = (p.x + 180.0f) * DEG2RAD;
  float theta = (p.y + 90.0f) * DEG2RAD;

  float s, x;                    // s = sin(theta) >= 0, x = cos(theta)
  sincosf(theta, &s, &x);
  float sp, cp;                  // sin(phi), cos(phi)
  sincosf(phi, &sp, &cp);

  // cos(m*phi), sin(m*phi) via angle-addition recurrence (fully unrolled)
  float cm[L], sm[L];
  cm[0] = 1.0f; sm[0] = 0.0f;
  cm[1] = cp;   sm[1] = sp;
#pragma unroll
  for (int m = 2; m < L; ++m) {
    cm[m] = cm[m - 1] * cp - sm[m - 1] * sp;
    sm[m] = sm[m - 1] * cp + cm[m - 1] * sp;
  }

  float* orow = out + (size_t)i * (L * L);  // row base, 400 B -> 16B aligned
  float obuf[L * L];                        // compile-time indexed only
  float prev2[L], prev[L], cur[L];

#pragma unroll
  for (int l = 0; l < L; ++l) {
    // ---- Legendre row l (P_l^m for m=0..l), mirrors reference recurrences in f32
#pragma unroll
    for (int m = 0; m <= l; ++m) {
      if (m == l) {
        // diagonal: P[l][l] = -(2l-1) * s * P[l-1][l-1]  (Condon-Shortley)
        cur[m] = (l == 0) ? 1.0f : -(2.0f * l - 1.0f) * s * prev[l - 1];
      } else if (m == l - 1) {
        // P[m+1][m] = x * (2m+1) * P[m][m]
        cur[m] = x * (2.0f * l - 1.0f) * prev[l - 1];
      } else {
        cur[m] = ((2.0f * l - 1.0f) * x * prev[m] - (float)(l + m - 1) * prev2[m]) /
                 (float)(l - m);
      }
    }

    // ---- emit outputs for row l: order m = -l..l, flush float4 when full
#pragma unroll
    for (int m = -l; m <= l; ++m) {
      int am = m < 0 ? -m : m;
      float v;
      if (m == 0)      v = TAB.c[l][0]  * cur[0];
      else if (m > 0)  v = TAB.c[l][am] * cm[am] * cur[am];
      else             v = TAB.c[l][am] * sm[am] * cur[am];
      int idx = l * l + l + m;  // constant per unrolled instance
      obuf[idx] = v;
      if ((idx & 3) == 3) {
        float4 v4 = make_float4(obuf[idx - 3], obuf[idx - 2], obuf[idx - 1], obuf[idx]);
        *reinterpret_cast<float4*>(orow + (idx - 3)) = v4;
      }
    }

    // ---- roll Legendre state
#pragma unroll
    for (int m = 0; m < l; ++m) prev2[m] = prev[m];
#pragma unroll
    for (int m = 0; m <= l; ++m) prev[m] = cur[m];
  }
}

}  // namespace

extern "C" void kernel_launch(void* const* d_in, const int* in_sizes, int n_in,
                              void* d_out, int out_size, void* d_ws, size_t ws_size,
                              hipStream_t stream) {
  (void)n_in; (void)d_ws; (void)ws_size; (void)out_size;
  const float2* ll = (const float2*)d_in[0];
  float* out = (float*)d_out;
  int N = in_sizes[0] / 2;
  int block = 256;
  int grid = (N + block - 1) / block;
  sh_kernel<<<grid, block, 0, stream>>>(ll, out, N);
}

// Round 4
// 397.522 us; speedup vs baseline: 1.5032x; 1.5032x over previous
//
#include <hip/hip_runtime.h>
#include <math.h>

namespace {

constexpr int L = 10;
constexpr int NSH = L * L;    // 100 outputs per point
constexpr int ROWS = 64;      // points per block (1 wave)
constexpr int STRIDE = 101;   // LDS row stride in floats (odd -> conflict-free staging)

// compile-time sqrt (Newton)
constexpr double csqrt(double x) {
  double y = x > 1.0 ? x : 1.0;
  for (int i = 0; i < 64; ++i) y = 0.5 * (y + x / y);
  return y;
}
constexpr double dfact(int n) {
  double r = 1.0;
  for (int i = 2; i <= n; ++i) r *= (double)i;
  return r;
}

struct Tab { float c[L][L]; };
constexpr Tab make_tab() {
  Tab t{};
  constexpr double FOUR_PI = 12.566370614359172;
  constexpr double SQRT2  = 1.4142135623730951;
  for (int l = 0; l < L; ++l)
    for (int m = 0; m <= l; ++m) {
      double K = csqrt((2.0 * l + 1.0) / FOUR_PI * dfact(l - m) / dfact(l + m));
      t.c[l][m] = (float)((m == 0 ? 1.0 : SQRT2) * K);
    }
  return t;
}
constexpr Tab TAB = make_tab();

// reciprocal table for the (l-m) divisor, folded at compile time
struct RinvT { float r[L]; };
constexpr RinvT make_rinv() {
  RinvT t{};
  for (int d = 1; d < L; ++d) t.r[d] = (float)(1.0 / (double)d);
  return t;
}
constexpr RinvT RINV = make_rinv();

__global__ __launch_bounds__(ROWS) void sh_kernel(const float2* __restrict__ ll,
                                                  float* __restrict__ out, int N) {
  __shared__ float lds[ROWS * STRIDE];  // 25,856 B -> 6 blocks/CU
  const int tid = threadIdx.x;
  const int row0 = blockIdx.x * ROWS;
  const int i = row0 + tid;

  // per-row rotation of the 4 slots within each float4 group:
  // value idx (k = idx&3) of row r is stored at (idx&~3) + ((k + r) & 3).
  // Bijective within group; breaks the mod-4 bank lattice on the read side.
  int rot[4] = { (tid + 0) & 3, (tid + 1) & 3, (tid + 2) & 3, (tid + 3) & 3 };
  float* myrow = lds + tid * STRIDE;

  if (i < N) {
    float2 p = ll[i];  // coalesced 8B/lane
    constexpr float DEG2RAD = 0.017453292519943295f;
    float phi   = (p.x + 180.0f) * DEG2RAD;
    float theta = (p.y + 90.0f) * DEG2RAD;

    float s, x;   // s = sin(theta) >= 0, x = cos(theta)
    sincosf(theta, &s, &x);
    float sp, cp; // sin(phi), cos(phi)
    sincosf(phi, &sp, &cp);

    // cos(m*phi), sin(m*phi) via angle-addition (fully unrolled)
    float cm[L], sm[L];
    cm[0] = 1.0f; sm[0] = 0.0f;
    cm[1] = cp;   sm[1] = sp;
#pragma unroll
    for (int m = 2; m < L; ++m) {
      cm[m] = cm[m - 1] * cp - sm[m - 1] * sp;
      sm[m] = sm[m - 1] * cp + cm[m - 1] * sp;
    }

    float prev2[L], prev[L], cur[L];

#pragma unroll
    for (int l = 0; l < L; ++l) {
      // Legendre row l (P_l^m for m=0..l) — mirrors reference f32 recurrences
      // (division replaced by constexpr reciprocal multiply, <=1 ulp)
#pragma unroll
      for (int m = 0; m <= l; ++m) {
        if (m == l) {
          cur[m] = (l == 0) ? 1.0f : -(2.0f * l - 1.0f) * s * prev[l - 1];
        } else if (m == l - 1) {
          cur[m] = x * (2.0f * l - 1.0f) * prev[l - 1];
        } else {
          cur[m] = ((2.0f * l - 1.0f) * x * prev[m] - (float)(l + m - 1) * prev2[m]) *
                   RINV.r[l - m];
        }
      }

      // emit outputs for row l straight into LDS (compile-time idx)
#pragma unroll
      for (int m = -l; m <= l; ++m) {
        int am = m < 0 ? -m : m;
        float v;
        if (m == 0)      v = TAB.c[l][0]  * cur[0];
        else if (m > 0)  v = TAB.c[l][am] * cm[am] * cur[am];
        else             v = TAB.c[l][am] * sm[am] * cur[am];
        int idx = l * l + l + m;                    // constant per unrolled instance
        myrow[(idx & ~3) + rot[idx & 3]] = v;       // ds_write_b32, imm offset
      }

      // roll Legendre state
#pragma unroll
      for (int m = 0; m < l; ++m) prev2[m] = prev[m];
#pragma unroll
      for (int m = 0; m <= l; ++m) prev[m] = cur[m];
    }
  }

  __syncthreads();

  // coalesced write of the block's contiguous 64x100-float span
  const size_t base  = (size_t)row0 * NSH;
  const size_t limit = (size_t)N * NSH;
#pragma unroll
  for (int it = 0; it < NSH / 4; ++it) {   // 25 float4 groups per thread
    int g  = it * ROWS + tid;              // group index in tile, < 1600
    int r  = (g * 1311) >> 15;             // g / 25 (exact for g < 4683)
    int cc = g - r * 25;                   // g % 25
    int fb = r * STRIDE + cc * 4;
    float4 v;
    v.x = lds[fb + ((r + 0) & 3)];
    v.y = lds[fb + ((r + 1) & 3)];
    v.z = lds[fb + ((r + 2) & 3)];
    v.w = lds[fb + ((r + 3) & 3)];
    size_t e = base + (size_t)g * 4;
    if (e < limit)
      *reinterpret_cast<float4*>(out + e) = v;  // wave: 1 KB contiguous per instr
  }
}

}  // namespace

extern "C" void kernel_launch(void* const* d_in, const int* in_sizes, int n_in,
                              void* d_out, int out_size, void* d_ws, size_t ws_size,
                              hipStream_t stream) {
  (void)n_in; (void)d_ws; (void)ws_size; (void)out_size;
  const float2* ll = (const float2*)d_in[0];
  float* out = (float*)d_out;
  int N = in_sizes[0] / 2;
  int grid = (N + ROWS - 1) / ROWS;
  sh_kernel<<<grid, ROWS, 0, stream>>>(ll, out, N);
}